// Round 1
// baseline (224.916 us; speedup 1.0000x reference)
//
#include <hip/hip_runtime.h>
#include <math.h>

#define Bn 16
#define Tn 2048
#define Fn 1025
#define F4 257      // ceil(1025/4)
#define FPAD 1028
#define Dn 64
#define TB 16
#define EPSF 1e-6f

__device__ inline float waveReduceSum(float v) {
#pragma unroll
  for (int off = 32; off > 0; off >>= 1) v += __shfl_xor(v, off, 64);
  return v;
}

// ---------------- prep: basis in [f/4][d][4] layout + spacing outputs ----------------
__global__ __launch_bounds__(256) void prep_kernel(
    const float* __restrict__ freq, const float* __restrict__ spacing,
    float* __restrict__ basis4, float* __restrict__ out2, float* __restrict__ out3) {
  __shared__ float wsum[4];
  const int d = blockIdx.x;
  const int tid = threadIdx.x;
  const float sp = fmaxf(spacing[d], 1e-6f);

  float pv[5];
  float lsum = 0.f;
  int j = 0;
  for (int f = tid; f < FPAD; f += 256, ++j) {
    float p = 0.f;
    if (f < Fn) {
      float fr = freq[f];
      float arg = 6.2831853071795864769 * (double)(fr / sp);
      p = 0.5f * (1.0f + (float)cos((double)arg));
      lsum += p;
    }
    pv[j] = p;
  }
  float s = waveReduceSum(lsum);
  if ((tid & 63) == 0) wsum[tid >> 6] = s;
  __syncthreads();
  float total = wsum[0] + wsum[1] + wsum[2] + wsum[3];
  float mean = total * (1.0f / 1025.0f);
  float inv = 1.0f / fmaxf(mean, EPSF);

  j = 0;
  for (int f = tid; f < FPAD; f += 256, ++j) {
    basis4[((size_t)(f >> 2) * Dn + d) * 4 + (f & 3)] = pv[j] * inv;
  }
  if (tid == 0) {
    out2[d] = spacing[d];
    out3[d] = 17150.0f / sp;  // 100*343/(2*max(sp,1e-6))
  }
}

// ---------------- main fused kernel ----------------
__global__ __launch_bounds__(256) void main_kernel(
    const float* __restrict__ phase, const float* __restrict__ comb,
    const float* __restrict__ scalar, const float* __restrict__ obs_m,
    const float* __restrict__ rel_m, const float* __restrict__ stpacc,
    const float* __restrict__ basis4,
    float* __restrict__ out0, float* __restrict__ out1) {
  __shared__ float u_lds[TB][FPAD];   // 65792 B
  __shared__ float rowScale[TB];

  const int tid = threadIdx.x;
  const int lane = tid & 63;
  const int w = tid >> 6;
  const int blk = blockIdx.x;
  const int b = blk / (Tn / TB);
  const int t0 = (blk % (Tn / TB)) * TB;

  // ---- Phase 1: trough rows into LDS (wave w owns rows 4w..4w+3) ----
#pragma unroll
  for (int k = 0; k < 4; ++k) {
    const int tl = 4 * w + k;
    const int t = t0 + tl;
    const size_t bt = (size_t)(b * Tn + t);
    const float* prow = phase + bt * Fn;
    float slm = 0.f;
#pragma unroll
    for (int it = 0; it < 17; ++it) {
      int f = lane + it * 64;
      float lm = 0.f;
      if (f < Fn) { lm = prow[f]; slm += lm; }
      if (f < FPAD) u_lds[tl][f] = lm;   // pad lanes store 0
    }
    slm = waveReduceSum(slm);
    const float mean_lm = slm * (1.0f / 1025.0f);

    const float* c0row = comb + ((size_t)(b * 2 + 0) * Tn + t) * Fn;
    const float* c1row = comb + ((size_t)(b * 2 + 1) * Tn + t) * Fn;
    float su = 0.f;
#pragma unroll
    for (int it = 0; it < 17; ++it) {
      int f = lane + it * 64;
      if (f < Fn) {
        float lm = u_lds[tl][f];
        float tr = fmaxf(mean_lm - lm, 0.f);
        float d1 = fabsf(c1row[f]) + 0.25f * fabsf(c0row[f]);
        float u = tr * (1.f + d1);
        u_lds[tl][f] = u;
        su += u;
      }
    }
    su = waveReduceSum(su);
    if (lane == 0) rowScale[tl] = 1.0f / fmaxf(su * (1.0f / 1025.0f), EPSF);
  }
  // no __syncthreads needed: all LDS reuse below is wave-internal

  // ---- Phase 2: segmented dot products (d = lane; wave w covers its 4 rows) ----
  const int d = lane;
  float acc[4] = {0.f, 0.f, 0.f, 0.f};
  float snap0[4], snap1[4], snap2[4];
  const float4* bq = (const float4*)basis4;

  auto doChunk = [&](int c) {
    float4 bv = bq[(size_t)c * Dn + d];
#pragma unroll
    for (int k = 0; k < 4; ++k) {
      float4 uv = *(const float4*)&u_lds[4 * w + k][c * 4];
      acc[k] += uv.x * bv.x + uv.y * bv.y + uv.z * bv.z + uv.w * bv.w;
    }
  };
  auto doChunkSplit = [&](int c, float* snp) {
    float4 bv = bq[(size_t)c * Dn + d];
    float4 uv[4];
#pragma unroll
    for (int k = 0; k < 4; ++k) uv[k] = *(const float4*)&u_lds[4 * w + k][c * 4];
#pragma unroll
    for (int k = 0; k < 4; ++k) acc[k] += uv[k].x * bv.x + uv[k].y * bv.y;
#pragma unroll
    for (int k = 0; k < 4; ++k) snp[k] = acc[k];
#pragma unroll
    for (int k = 0; k < 4; ++k) acc[k] += uv[k].z * bv.z + uv[k].w * bv.w;
  };

  for (int c = 0; c < 5; ++c) doChunk(c);      // band0: f 0..21
  doChunkSplit(5, snap0);                       // boundary at f=22
  for (int c = 6; c < 21; ++c) doChunk(c);     // band1: f 22..85
  doChunkSplit(21, snap1);                      // boundary at f=86
  for (int c = 22; c < 85; ++c) doChunk(c);    // band2: f 86..341
  doChunkSplit(85, snap2);                      // boundary at f=342
  for (int c = 86; c < F4; ++c) doChunk(c);    // band3: f 342..1024 (+zero pad)

  // ---- Phase 3: remaining channels + writes ----
  const float invD0 = 1.0f / 22.0f, invD1 = 1.0f / 64.0f,
              invD2 = 1.0f / 256.0f, invD3 = 1.0f / 683.0f;
#pragma unroll
  for (int k = 0; k < 4; ++k) {
    const int tl = 4 * w + k;
    const int t = t0 + tl;
    const size_t bt = (size_t)(b * Tn + t);

    // stp channel (mean over D=64 via wave reduce)
    float sv = fmaxf(stpacc[bt * Dn + lane], 0.f);
    float ssum = waveReduceSum(sv);
    float stp = sv / fmaxf(ssum * (1.0f / 64.0f), EPSF);

    float4 sc = *(const float4*)(scalar + bt * 4);
    float4 om = *(const float4*)(obs_m + bt * 4);
    float4 rm = *(const float4*)(rel_m + bt * 4);
    float obs_q = (om.x + om.y + om.z + om.w) * 0.25f;
    float rel_q = (rm.x + rm.y + rm.z + rm.w) * 0.25f;
    float is_snd = fminf(fmaxf(sc.x, 0.f), 1.f);
    float rho = fabsf(fminf(fmaxf(sc.y, -1.f), 1.f));

    float rs = rowScale[tl];
    float c0 = acc[k] * rs * (1.0f / 1025.0f);
    float s0 = snap0[k];
    float s1 = snap1[k] - snap0[k];
    float s2 = snap2[k] - snap1[k];
    float s3 = acc[k] - snap2[k];
    float c1 = s0 * rs * invD0;
    float c2 = s1 * rs * invD1;
    float c3 = s2 * rs * invD2;
    float c4 = s3 * rs * invD3;

    float mean10 = (c0 + c1 + c2 + c3 + c4 + stp + obs_q + rel_q + is_snd + rho) * 0.1f;
    float logit = mean10 * (0.5f + 0.5f * is_snd);

    float2* op = (float2*)(out0 + (bt * Dn + lane) * 10);
    op[0] = make_float2(c0, c1);
    op[1] = make_float2(c2, c3);
    op[2] = make_float2(c4, stp);
    op[3] = make_float2(obs_q, rel_q);
    op[4] = make_float2(is_snd, rho);
    out1[bt * Dn + lane] = logit;
  }
}

extern "C" void kernel_launch(void* const* d_in, const int* in_sizes, int n_in,
                              void* d_out, int out_size, void* d_ws, size_t ws_size,
                              hipStream_t stream) {
  const float* phase   = (const float*)d_in[0];
  const float* comb    = (const float*)d_in[1];
  const float* scalar  = (const float*)d_in[2];
  const float* obs_m   = (const float*)d_in[3];
  const float* rel_m   = (const float*)d_in[4];
  const float* stpacc  = (const float*)d_in[5];
  const float* freq    = (const float*)d_in[6];
  const float* spacing = (const float*)d_in[7];

  float* out  = (float*)d_out;
  float* out0 = out;                                    // (B,T,D,10)
  float* out1 = out + (size_t)Bn * Tn * Dn * 10;        // (B,T,D)
  float* out2 = out1 + (size_t)Bn * Tn * Dn;            // (D,)
  float* out3 = out2 + Dn;                              // (D,)

  float* basis4 = (float*)d_ws;                         // F4*64*4 floats = 263168 B

  prep_kernel<<<Dn, 256, 0, stream>>>(freq, spacing, basis4, out2, out3);
  main_kernel<<<Bn * Tn / TB, 256, 0, stream>>>(
      phase, comb, scalar, obs_m, rel_m, stpacc, basis4, out0, out1);
}